// Round 15
// baseline (153.384 us; speedup 1.0000x reference)
//
#include <hip/hip_runtime.h>
#include <hip/hip_bf16.h>

// ConformerAttention on MI355X (gfx950)
// B=2 T=2048 D=512 NH=8 DK=64 P=4095
// rel_shift identity: scores_bd[t,s] = q_v[t] . pos[s - t + 2047]
// -> banded GEMM with rolling 128-slot f32 ring (each band column computed once).
// R15 = R14 + single-buffer T14 prefetch in attn: K/V/pos global loads issued
// AFTER barrier2 (hidden under compute); barrier1's compiler-emitted vmcnt(0)
// drain is exactly where the data is needed (ds_write from regs). Staging
// critical section = 8 ds_writes. Tree max/sum (depth 5 vs serial 31).
// 3 launches: front (QKV+pos+maskw), attn, back (combine+out-GEMM).

typedef __attribute__((ext_vector_type(8))) short short8;
typedef __attribute__((ext_vector_type(16))) float f32x16;
typedef __attribute__((ext_vector_type(4))) float f32x4;
typedef __attribute__((ext_vector_type(2))) unsigned int uint2v;

#define C2F 0.18033688011112043f   // 0.125 * log2(e)
#define MOFF 144269.504088896f     // 100000 * log2(e)

static __device__ __forceinline__ unsigned short f2bf(float x) {
    unsigned int u = __builtin_bit_cast(unsigned int, x);
    u += 0x7FFFu + ((u >> 16) & 1u);   // RNE
    return (unsigned short)(u >> 16);
}
static __device__ __forceinline__ unsigned int cvt2bf(float lo, float hi) {
    // v_cvt_pk_bf16_f32 via the official intrinsic (RNE, matches f2bf)
    __hip_bfloat162 h = __float22bfloat162_rn(make_float2(lo, hi));
    unsigned int r;
    __builtin_memcpy(&r, &h, 4);
    return r;
}
static __device__ __forceinline__ float exp2v(float x) {
    return __builtin_amdgcn_exp2f(x);   // bare v_exp_f32
}
static __device__ __forceinline__ float bf2f(unsigned short u) {
    return __builtin_bit_cast(float, (unsigned int)u << 16);
}
static __device__ __forceinline__ f32x16 zero16() {
    f32x16 v;
#pragma unroll
    for (int i = 0; i < 16; ++i) v[i] = 0.0f;
    return v;
}
static __device__ __forceinline__ f32x16 mfma_bf(short8 a, short8 b, f32x16 c) {
    return __builtin_amdgcn_mfma_f32_32x32x16_bf16(a, b, c, 0, 0, 0);
}
static __device__ __forceinline__ short8 load8f(const float* base, size_t eoff) {
    const float4* p = (const float4*)(base + eoff);
    float4 a = p[0], b = p[1];
    union { unsigned int u[4]; short8 s; } r;
    r.u[0] = cvt2bf(a.x, a.y);
    r.u[1] = cvt2bf(a.z, a.w);
    r.u[2] = cvt2bf(b.x, b.y);
    r.u[3] = cvt2bf(b.z, b.w);
    return r.s;
}

// ---------------------------------------------------------------- front
// 640 blocks: [0,384) QKV GEMM (M=4096,N=1536), [384,512) pos GEMM (M=4095,
// N=512), [512,640) maskw precompute. GEMM: 128x128 tile, 4 waves, BK=32.
__global__ __launch_bounds__(256) void front_kernel(
    const float* __restrict__ x, const float* __restrict__ wqkv,
    const float* __restrict__ pe, const float* __restrict__ wpos,
    unsigned short* __restrict__ qu, unsigned short* __restrict__ qv,
    unsigned short* __restrict__ kb, unsigned short* __restrict__ vt,
    unsigned short* __restrict__ posb,
    const float* __restrict__ bu, const float* __restrict__ bv,
    const unsigned char* __restrict__ mk, unsigned long long* __restrict__ mwout)
{
    const int tid = threadIdx.x;
    const int bid = blockIdx.x;

    if (bid >= 512) {
        // ---- maskw role: words[(b*2048+t)*32+itg] bit s = any(mask byte)
        int base = (bid - 512) * 256 + tid;
#pragma unroll 1
        for (int idx = base; idx < 131072; idx += 32768) {
            const unsigned long long* row =
                (const unsigned long long*)(mk + (size_t)(idx >> 5) * 2048) +
                (size_t)(idx & 31) * 8;
            unsigned long long w = 0;
#pragma unroll
            for (int k = 0; k < 8; ++k) {
                unsigned long long v = row[k];
                v |= v >> 4; v |= v >> 2; v |= v >> 1;
                v &= 0x0101010101010101ull;
                w |= ((v * 0x0102040810204080ull) >> 56) << (k * 8);
            }
            mwout[idx] = w;
        }
        return;
    }

    const int role = bid >= 384 ? 1 : 0;       // 0 = QKV, 1 = pos
    const int lb = role ? bid - 384 : bid;
    const int bx = role ? (lb & 3) : (lb % 12);
    const int by = role ? (lb >> 2) : (lb / 12);
    const float* A  = role ? pe : x;
    const float* Bw = role ? wpos : wqkv;
    const int M = role ? 4095 : 4096;

    __shared__ __align__(16) unsigned short As[128 * 32];
    __shared__ __align__(16) unsigned short Bs[128 * 32];

    const int lane = tid & 63;
    const int l31 = lane & 31;
    const int h = (lane >> 5) & 1;
    const int wid = tid >> 6;
    const int wm = wid >> 1, wn = wid & 1;
    const int m0 = by * 128, n0 = bx * 128;

    f32x16 acc[2][2];
#pragma unroll
    for (int mt = 0; mt < 2; ++mt)
#pragma unroll
        for (int nt = 0; nt < 2; ++nt) acc[mt][nt] = zero16();

    const int row_s = tid >> 2;
    const int q_s = tid & 3;

#pragma unroll 1
    for (int k0 = 0; k0 < 512; k0 += 32) {
        __syncthreads();
#pragma unroll
        for (int rep = 0; rep < 2; ++rep) {
            int row = row_s + rep * 64;
            int ar = m0 + row; if (ar > M - 1) ar = M - 1;
            short8 av = load8f(A, (size_t)ar * 512 + k0 + q_s * 8);
            *(short8*)((char*)As + ((row * 64 + q_s * 16) ^ ((row & 3) << 4))) = av;
            int br = n0 + row;
            short8 bv8 = load8f(Bw, (size_t)br * 512 + k0 + q_s * 8);
            *(short8*)((char*)Bs + ((row * 64 + q_s * 16) ^ ((row & 3) << 4))) = bv8;
        }
        __syncthreads();

        short8 af[2][2], bf[2][2];
#pragma unroll
        for (int mt = 0; mt < 2; ++mt)
#pragma unroll
            for (int ks = 0; ks < 2; ++ks) {
                int row = wm * 64 + mt * 32 + l31;
                af[mt][ks] = *(const short8*)((char*)As +
                    ((row * 64 + ks * 32 + h * 16) ^ ((row & 3) << 4)));
            }
#pragma unroll
        for (int nt = 0; nt < 2; ++nt)
#pragma unroll
            for (int ks = 0; ks < 2; ++ks) {
                int row = wn * 64 + nt * 32 + l31;
                bf[nt][ks] = *(const short8*)((char*)Bs +
                    ((row * 64 + ks * 32 + h * 16) ^ ((row & 3) << 4)));
            }
#pragma unroll
        for (int mt = 0; mt < 2; ++mt)
#pragma unroll
            for (int nt = 0; nt < 2; ++nt)
#pragma unroll
                for (int ks = 0; ks < 2; ++ks)
                    acc[mt][nt] = mfma_bf(af[mt][ks], bf[nt][ks], acc[mt][nt]);
    }

#pragma unroll
    for (int mt = 0; mt < 2; ++mt)
#pragma unroll
        for (int nt = 0; nt < 2; ++nt) {
            int Ncol = n0 + wn * 64 + nt * 32 + l31;
#pragma unroll
            for (int r = 0; r < 16; ++r) {
                int Mrow = m0 + wm * 64 + mt * 32 + (r & 3) + ((r >> 2) << 3) + h * 4;
                float v = acc[mt][nt][r];
                if (role == 0) {
                    int b = Mrow >> 11, t = Mrow & 2047;
                    int sec = Ncol >> 9, hd = (Ncol >> 6) & 7, dk = Ncol & 63;
                    if (sec == 0) {
                        // q_u/q_v pre-scaled into exp2 domain (C2F = 0.125*log2e)
                        size_t idx = ((size_t)((b * 8 + hd) * 2048 + t)) * 64 + dk;
                        qu[idx] = f2bf((v + bu[hd * 64 + dk]) * C2F);
                        qv[idx] = f2bf((v + bv[hd * 64 + dk]) * C2F);
                    } else if (sec == 1) {
                        kb[((size_t)((b * 8 + hd) * 2048 + t)) * 64 + dk] = f2bf(v);
                    } else {
                        // v transposed: vt[bh][dk][t]
                        vt[((size_t)((b * 8 + hd) * 64 + dk)) * 2048 + t] = f2bf(v);
                    }
                } else {
                    if (Mrow < M) {
                        int hd = Ncol >> 6, dk = Ncol & 63;
                        posb[((size_t)(hd * 4095 + Mrow)) * 64 + dk] = f2bf(v);
                    }
                }
            }
        }
}

// ---------------------------------------------------------------- fused attention
// grid (32 tb, 16 bh, 2 sc), 128 threads = 2 waves; wave owns 32 t-rows,
// block sweeps s in [sc, sc+1024). Swapped-operand S^T = mfma(K, Q^T);
// lane pair (l31, l31+32) shares a t-row (32x32 C/D: col=lane&31).
// Scores in exp2 domain (qu/qv pre-scaled); f32 E-ring (R5-proven).
// Single-buffer prefetch: it+1's K/V/pos loads issued after barrier2, their
// vmcnt(0) drain happens at the NEXT barrier1 (hidden under compute).
__global__ __launch_bounds__(128) void attn_kernel(
    const unsigned short* __restrict__ qup, const unsigned short* __restrict__ qvp,
    const unsigned short* __restrict__ kp,  const unsigned short* __restrict__ vtp,
    const unsigned short* __restrict__ posp,
    const unsigned long long* __restrict__ mwp,
    unsigned short* __restrict__ opart,
    float* __restrict__ mstat, float* __restrict__ lstat)
{
    const int tb = blockIdx.x, bh = blockIdx.y, scb = blockIdx.z;
    const int b = bh >> 3, head = bh & 7;
    const int t0 = tb * 64;
    const int sc = scb << 10;

    const int lane = threadIdx.x & 63;
    const int l31 = lane & 31;
    const int h = (lane >> 5) & 1;
    const int h4 = h * 4;
    const int wid = threadIdx.x >> 6;

    __shared__ __align__(16) unsigned short Kss[64 * 64];
    __shared__ __align__(16) unsigned short Vts[64 * 64];
    __shared__ __align__(16) float Ew[2 * 32 * 132];   // per-wave f32 ring [t][slot]

    const unsigned short* posg = posp + (size_t)head * 4095 * 64;
    const unsigned short* kg0 = kp + (size_t)bh * 2048 * 64;
    const unsigned short* vtg = vtp + (size_t)bh * 64 * 2048;
    const int t = t0 + wid * 32 + l31;

    // Q fragments (B-operand: col = t, k = ks*16 + h*8 + j), exp2-domain scaled
    const size_t qoff = ((size_t)bh * 2048 + t) * 64;
    short8 qu_f[4], qv_f[4];
#pragma unroll
    for (int ks = 0; ks < 4; ++ks) {
        qu_f[ks] = *(const short8*)(qup + qoff + ks * 16 + h * 8);
        qv_f[ks] = *(const short8*)(qvp + qoff + ks * 16 + h * 8);
    }

    float* ewp = Ew + (wid * 32 + l31) * 132;

    auto load_pos = [&](int c_r0, short8 (&pf)[8]) {
#pragma unroll
        for (int et = 0; et < 2; ++et) {
            int r = c_r0 + et * 32 + l31;
            r = min(r, 4094);      // clamped rows land in never-gathered slots
#pragma unroll
            for (int ks = 0; ks < 4; ++ks)
                pf[et * 4 + ks] = *(const short8*)(posg + (size_t)r * 64 + ks * 16 + h * 8);
        }
    };
    // E^T chunk: rows = 64 band slots, cols = t. Ring row shared by the h-pair
    // of THIS wave only (disjoint slot subsets qd*8 + h4 + j).
    auto e_gemm = [&](const short8 (&pf)[8], int slotb) {
#pragma unroll
        for (int et = 0; et < 2; ++et) {
            f32x16 ea = zero16();
#pragma unroll
            for (int ks = 0; ks < 4; ++ks)
                ea = mfma_bf(pf[et * 4 + ks], qv_f[ks], ea);
#pragma unroll
            for (int qd = 0; qd < 4; ++qd) {
                f32x4 w;
                w[0] = ea[qd * 4 + 0]; w[1] = ea[qd * 4 + 1];
                w[2] = ea[qd * 4 + 2]; w[3] = ea[qd * 4 + 3];
                *(f32x4*)(ewp + slotb + et * 32 + qd * 8 + h4) = w;
            }
        }
    };

    const int st_row = threadIdx.x >> 3;     // 0..15 (+16 per rep)
    const int st_q = threadIdx.x & 7;

    auto stage_issue = [&](int it, short8 (&kr)[4], short8 (&vr)[4]) {
        const int s0a = sc + it * 64;
#pragma unroll
        for (int rep = 0; rep < 4; ++rep) {
            int row = st_row + rep * 16;
            kr[rep] = *(const short8*)(kg0 + ((size_t)(s0a + row)) * 64 + st_q * 8);
            vr[rep] = *(const short8*)(vtg + (size_t)row * 2048 + s0a + st_q * 8);
        }
    };
    auto stage_write = [&](const short8 (&kr)[4], const short8 (&vr)[4]) {
#pragma unroll
        for (int rep = 0; rep < 4; ++rep) {
            int row = st_row + rep * 16;
            int off = (row * 128 + st_q * 16) ^ ((row & 7) << 4);
            *(short8*)((char*)Kss + off) = kr[rep];
            *(short8*)((char*)Vts + off) = vr[rep];
        }
    };

    // 64-aligned ring origin (R5/R8-verified coverage)
    const int c0 = sc + 1984 - t0;
    short8 kr[4], vr[4], pf[8];
    stage_issue(0, kr, vr);                  // prefetch first K/V tile
    {
        short8 pf0[8];
        load_pos(c0, pf0);      e_gemm(pf0, c0 & 127);
        load_pos(c0 + 64, pf0); e_gemm(pf0, (c0 + 64) & 127);
    }
    load_pos(c0 + 128, pf);                  // prefetch first ring chunk

    float m = -3.0e38f, lsum = 0.0f;
    f32x16 o_acc[2];
    o_acc[0] = zero16(); o_acc[1] = zero16();

    const size_t mw_base = ((size_t)(b * 2048 + t)) * 32 + (sc >> 6);

#pragma unroll 1
    for (int it = 0; it < 16; ++it) {
        __syncthreads();   // prior tile reads done; vmcnt(0) drain = kr/vr ready
        stage_write(kr, vr);
        unsigned long long mw = mwp[mw_base + it];
        __syncthreads();   // staged tiles visible
        // ---- issue NEXT iter's loads; latency hides under this iter's compute
        if (it < 15) {
            stage_issue(it + 1, kr, vr);
        }

        // ---- S^T = K . Qu^T (already exp2-domain scaled via qu)
        f32x16 sacc[2];
        sacc[0] = zero16(); sacc[1] = zero16();
#pragma unroll
        for (int st2 = 0; st2 < 2; ++st2)
#pragma unroll
            for (int ks = 0; ks < 4; ++ks) {
                int row = st2 * 32 + l31;
                short8 a = *(const short8*)((char*)Kss +
                    ((row * 128 + ks * 32 + h * 16) ^ ((row & 7) << 4)));
                sacc[st2] = mfma_bf(a, qu_f[ks], sacc[st2]);
            }

        // ---- add banded BD from ring (both terms pre-scaled), mask
        const int s0a = sc + it * 64;
        const int sb = s0a - t + 2047;
        float sv[32];
#pragma unroll
        for (int st2 = 0; st2 < 2; ++st2)
#pragma unroll
            for (int r = 0; r < 16; ++r) {
                int slot = (sb + st2 * 32 + (r & 3) + ((r >> 2) << 3) + h4) & 127;
                sv[st2 * 16 + r] = sacc[st2][r] + ewp[slot];
            }
        if (__any(mw != 0ull)) {
#pragma unroll
            for (int st2 = 0; st2 < 2; ++st2)
#pragma unroll
                for (int r = 0; r < 16; ++r) {
                    int s_loc = st2 * 32 + (r & 3) + ((r >> 2) << 3) + h4;
                    if ((mw >> s_loc) & 1ull)
                        sv[st2 * 16 + r] = sacc[st2][r] - MOFF;
                }
        }

        // ---- online softmax (exp2 domain, bare v_exp), tree reductions,
        //      pair-combined across lane^32
        float tm[16];
#pragma unroll
        for (int i = 0; i < 16; ++i) tm[i] = fmaxf(sv[i], sv[i + 16]);
#pragma unroll
        for (int s2 = 8; s2 > 0; s2 >>= 1)
#pragma unroll
            for (int i = 0; i < 8; ++i)
                if (i < s2) tm[i] = fmaxf(tm[i], tm[i + s2]);
        float mx = fmaxf(tm[0], __shfl_xor(tm[0], 32));
        float mnew = fmaxf(m, mx);
        float alpha = exp2v(m - mnew);
        m = mnew;
        float ts[16];
#pragma unroll
        for (int i = 0; i < 16; ++i) {
            sv[i] = exp2v(sv[i] - mnew);
            sv[i + 16] = exp2v(sv[i + 16] - mnew);
            ts[i] = sv[i] + sv[i + 16];
        }
#pragma unroll
        for (int s2 = 8; s2 > 0; s2 >>= 1)
#pragma unroll
            for (int i = 0; i < 8; ++i)
                if (i < s2) ts[i] += ts[i + s2];
        float psum = ts[0] + __shfl_xor(ts[0], 32);
        lsum = lsum * alpha + psum;
        o_acc[0] = o_acc[0] * alpha;
        o_acc[1] = o_acc[1] * alpha;

        // ---- pack P^T into B-fragments (cvt_pk pairs + symmetric exchange)
        short8 pfrag[4];
#pragma unroll
        for (int st2 = 0; st2 < 2; ++st2) {
            unsigned int X[8];
#pragma unroll
            for (int qd = 0; qd < 4; ++qd) {
                X[qd * 2 + 0] = cvt2bf(sv[st2 * 16 + qd * 4 + 0], sv[st2 * 16 + qd * 4 + 1]);
                X[qd * 2 + 1] = cvt2bf(sv[st2 * 16 + qd * 4 + 2], sv[st2 * 16 + qd * 4 + 3]);
            }
#pragma unroll
            for (int f = 0; f < 2; ++f) {
                unsigned int a0 = X[4 * f + 0], a1 = X[4 * f + 1];
                unsigned int b0 = X[4 * f + 2], b1 = X[4 * f + 3];
                unsigned int sa0 = (unsigned int)__shfl_xor((int)a0, 32);
                unsigned int sa1 = (unsigned int)__shfl_xor((int)a1, 32);
                unsigned int sb0 = (unsigned int)__shfl_xor((int)b0, 32);
                unsigned int sb1 = (unsigned int)__shfl_xor((int)b1, 32);
                union { unsigned int u[4]; short8 s8; } uu;
                uu.u[0] = h ? sb0 : a0;
                uu.u[1] = h ? sb1 : a1;
                uu.u[2] = h ? b0 : sa0;
                uu.u[3] = h ? b1 : sa1;
                pfrag[st2 * 2 + f] = uu.s8;
            }
        }

        // ---- O^T += V^T . P^T
#pragma unroll
        for (int dkt = 0; dkt < 2; ++dkt)
#pragma unroll
            for (int f = 0; f < 4; ++f) {
                int row = dkt * 32 + l31;
                short8 a = *(const short8*)((char*)Vts +
                    ((row * 128 + f * 32 + h * 16) ^ ((row & 7) << 4)));
                o_acc[dkt] = mfma_bf(a, pfrag[f], o_acc[dkt]);
            }

        // ---- produce this iter's ring chunk, then prefetch next chunk's pos
        if (it < 15) {
            e_gemm(pf, (c0 + 128 + 64 * it) & 127);
            if (it < 14) load_pos(c0 + 192 + 64 * it, pf);
        }
    }

    // ---- epilogue: normalized bf16 partials + stats (log2-domain m)
    float inv = 1.0f / lsum;
    if (m <= -9.0e4f) inv = 0.0f;
    size_t obase = (((size_t)scb * 16 + bh) * 2048 + t) * 64;
#pragma unroll
    for (int dkt = 0; dkt < 2; ++dkt)
#pragma unroll
        for (int qd = 0; qd < 4; ++qd) {
            int dk0 = dkt * 32 + qd * 8 + h4;
            uint2v u;
            u.x = cvt2bf(o_acc[dkt][qd * 4 + 0] * inv, o_acc[dkt][qd * 4 + 1] * inv);
            u.y = cvt2bf(o_acc[dkt][qd * 4 + 2] * inv, o_acc[dkt][qd * 4 + 3] * inv);
            *(uint2v*)(opart + obase + dk0) = u;
        }
    if (h == 0) {
        size_t sidx = ((size_t)scb * 16 + bh) * 2048 + t;
        mstat[sidx] = m;
        lstat[sidx] = lsum;
    }
}

// ---------------------------------------------------------------- back
// out-GEMM (M=4096, N=512) with 2-way combine fused into A staging.
// Stats are log2-domain -> exp2 weights (bare v_exp).
__global__ __launch_bounds__(256) void back_kernel(
    const unsigned short* __restrict__ opart, const float* __restrict__ wout,
    const float* __restrict__ mstat, const float* __restrict__ lstat,
    float* __restrict__ o_f)
{
    __shared__ __align__(16) unsigned short As[128 * 32];
    __shared__ __align__(16) unsigned short Bs[128 * 32];

    const int tid = threadIdx.x;
    const int lane = tid & 63;
    const int l31 = lane & 31;
    const int h = (lane >> 5) & 1;
    const int wid = tid >> 6;
    const int wm = wid >> 1, wn = wid & 1;
    const int m0 = blockIdx.y * 128, n0 = blockIdx.x * 128;

    f32x16 acc[2][2];
#pragma unroll
    for (int mt = 0; mt < 2; ++mt)
#pragma unroll
        for (int nt = 0; nt < 2; ++nt) acc[mt][nt] = zero16();

    const int row_s = tid >> 2;
    const int q_s = tid & 3;

#pragma unroll 1
    for (int k0 = 0; k0 < 512; k0 += 32) {
        __syncthreads();
#pragma unroll
        for (int rep = 0; rep < 2; ++rep) {
            int row = row_s + rep * 64;
            int ar = m0 + row;
            // ---- combine 2 normalized partials into the A operand
            int t_ = ar & 2047, b_ = ar >> 11;
            int c = k0 + q_s * 8;
            int head = c >> 6, dk0 = c & 63;
            int row2 = (b_ * 8 + head) * 2048 + t_;
            float m0s = mstat[row2], m1s = mstat[32768 + row2];
            float l0s = lstat[row2], l1s = lstat[32768 + row2];
            float Mx = fmaxf(m0s, m1s);
            float w0 = exp2v(m0s - Mx) * l0s, w1 = exp2v(m1s - Mx) * l1s;
            float den = w0 + w1;
            float inv = (den > 0.0f && Mx > -9.0e4f) ? 1.0f / den : 0.0f;
            w0 *= inv; w1 *= inv;
            short8 p0 = *(const short8*)(opart + (size_t)row2 * 64 + dk0);
            short8 p1 = *(const short8*)(opart + ((size_t)32768 + row2) * 64 + dk0);
            union { unsigned int u[4]; short8 s; } r;
#pragma unroll
            for (int j = 0; j < 4; ++j) {
                float lo = w0 * bf2f((unsigned short)p0[2 * j]) +
                           w1 * bf2f((unsigned short)p1[2 * j]);
                float hi = w0 * bf2f((unsigned short)p0[2 * j + 1]) +
                           w1 * bf2f((unsigned short)p1[2 * j + 1]);
                r.u[j] = cvt2bf(lo, hi);
            }
            *(short8*)((char*)As + ((row * 64 + q_s * 16) ^ ((row & 3) << 4))) = r.s;
            int br = n0 + row;
            short8 bv8 = load8f(wout, (size_t)br * 512 + k0 + q_s * 8);
            *(short8*)((char*)Bs + ((row * 64 + q_s * 16) ^ ((row & 3) << 4))) = bv8;
        }
        __syncthreads();

        short8 af[2][2], bf[2][2];
#pragma unroll
        for (int mt = 0; mt < 2; ++mt)
#pragma unroll
            for (int ks = 0; ks < 2; ++ks) {
                int row = wm * 64 + mt * 32 + l31;
                af[mt][ks] = *(const short8*)((char*)As +
                    ((row * 64 + ks * 32 + h * 16) ^ ((row & 3) << 4)));
            }
#pragma unroll
        for (int nt = 0; nt < 2; ++nt)
#pragma unroll
            for (int ks = 0; ks < 2; ++ks) {
                int row = wn * 64 + nt * 32 + l31;
                bf[nt][ks] = *(const short8*)((char*)Bs +
                    ((row * 64 + ks * 32 + h * 16) ^ ((row & 3) << 4)));
            }
#pragma unroll
        for (int mt = 0; mt < 2; ++mt)
#pragma unroll
            for (int nt = 0; nt < 2; ++nt)
#pragma unroll
                for (int ks = 0; ks < 2; ++ks)
                    acc[mt][nt] = mfma_bf(af[mt][ks], bf[nt][ks], acc[mt][nt]);
    }

#pragma unroll
    for (int mt = 0; mt < 2; ++mt)
#pragma unroll
        for (int nt = 0; nt < 2; ++nt) {
            int Ncol = n0 + wn * 64 + nt * 32 + l31;
#pragma unroll
            for (int r = 0; r < 16; ++r) {
                int Mrow = m0 + wm * 64 + mt * 32 + (r & 3) + ((r >> 2) << 3) + h * 4;
                o_f[(size_t)Mrow * 512 + Ncol] = acc[mt][nt][r];
            }
        }
}

// ---------------------------------------------------------------- host
extern "C" void kernel_launch(void* const* d_in, const int* in_sizes, int n_in,
                              void* d_out, int out_size, void* d_ws, size_t ws_size,
                              hipStream_t stream) {
    const float* x    = (const float*)d_in[0];
    const float* pe   = (const float*)d_in[1];
    const unsigned char* mask = (const unsigned char*)d_in[2];
    const float* wqkv = (const float*)d_in[3];
    const float* wpos = (const float*)d_in[4];
    const float* wout = (const float*)d_in[5];
    const float* bu   = (const float*)d_in[6];
    const float* bv   = (const float*)d_in[7];
    float* out = (float*)d_out;

    char* ws = (char*)d_ws;
    unsigned short* qu    = (unsigned short*)(ws + 0);
    unsigned short* qv    = (unsigned short*)(ws + 4194304);
    unsigned short* kb    = (unsigned short*)(ws + 8388608);
    unsigned short* vt    = (unsigned short*)(ws + 12582912);
    unsigned short* posb  = (unsigned short*)(ws + 16777216);   // 4,193,280 B
    unsigned long long* maskw = (unsigned long long*)(ws + 20971520); // 1 MB
    unsigned short* opart = (unsigned short*)(ws + 22020096);   // 8,388,608 B
    float* mstat          = (float*)(ws + 30408704);            // 262,144 B
    float* lstat          = (float*)(ws + 30670848);            // 262,144 B
    // total ws use ~31 MB, no overlaps

    front_kernel<<<640, 256, 0, stream>>>(
        x, wqkv, pe, wpos, qu, qv, kb, vt, posb, bu, bv, mask, maskw);
    attn_kernel<<<dim3(32, 16, 2), 128, 0, stream>>>(
        qu, qv, kb, vt, posb, maskw, opart, mstat, lstat);
    back_kernel<<<dim3(4, 32), 256, 0, stream>>>(
        opart, wout, mstat, lstat, out);
}

// Round 16
// 139.058 us; speedup vs baseline: 1.1030x; 1.1030x over previous
//
#include <hip/hip_runtime.h>
#include <hip/hip_bf16.h>

// ConformerAttention on MI355X (gfx950)
// B=2 T=2048 D=512 NH=8 DK=64 P=4095
// rel_shift identity: scores_bd[t,s] = q_v[t] . pos[s - t + 2047]
// -> banded GEMM with rolling 128-slot f32 ring (each band column computed once).
// R16 = R14 (best: attn 91.3us, total 147.8) + XCD-aware block swizzles (T1):
// blocks sharing operand panels land on the same XCD's L2 (attn: all 32 tb of
// one (bh,scb) share a 256KB K/V slice; front: 12 blocks share an x-panel).
// R15's prefetch reverted (twice-falsified). 3 launches.

typedef __attribute__((ext_vector_type(8))) short short8;
typedef __attribute__((ext_vector_type(16))) float f32x16;
typedef __attribute__((ext_vector_type(4))) float f32x4;
typedef __attribute__((ext_vector_type(2))) unsigned int uint2v;

#define C2F 0.18033688011112043f   // 0.125 * log2(e)
#define MOFF 144269.504088896f     // 100000 * log2(e)

static __device__ __forceinline__ unsigned short f2bf(float x) {
    unsigned int u = __builtin_bit_cast(unsigned int, x);
    u += 0x7FFFu + ((u >> 16) & 1u);   // RNE
    return (unsigned short)(u >> 16);
}
static __device__ __forceinline__ unsigned int cvt2bf(float lo, float hi) {
    // v_cvt_pk_bf16_f32 via the official intrinsic (RNE, matches f2bf)
    __hip_bfloat162 h = __float22bfloat162_rn(make_float2(lo, hi));
    unsigned int r;
    __builtin_memcpy(&r, &h, 4);
    return r;
}
static __device__ __forceinline__ float exp2v(float x) {
    return __builtin_amdgcn_exp2f(x);   // bare v_exp_f32
}
static __device__ __forceinline__ float bf2f(unsigned short u) {
    return __builtin_bit_cast(float, (unsigned int)u << 16);
}
static __device__ __forceinline__ f32x16 zero16() {
    f32x16 v;
#pragma unroll
    for (int i = 0; i < 16; ++i) v[i] = 0.0f;
    return v;
}
static __device__ __forceinline__ f32x16 mfma_bf(short8 a, short8 b, f32x16 c) {
    return __builtin_amdgcn_mfma_f32_32x32x16_bf16(a, b, c, 0, 0, 0);
}
static __device__ __forceinline__ short8 load8f(const float* base, size_t eoff) {
    const float4* p = (const float4*)(base + eoff);
    float4 a = p[0], b = p[1];
    union { unsigned int u[4]; short8 s; } r;
    r.u[0] = cvt2bf(a.x, a.y);
    r.u[1] = cvt2bf(a.z, a.w);
    r.u[2] = cvt2bf(b.x, b.y);
    r.u[3] = cvt2bf(b.z, b.w);
    return r.s;
}

// ---------------------------------------------------------------- front
// 640 blocks: [0,384) QKV GEMM (M=4096,N=1536), [384,512) pos GEMM (M=4095,
// N=512), [512,640) maskw. XCD swizzle: panel by pinned to xcd = by&7.
__global__ __launch_bounds__(256) void front_kernel(
    const float* __restrict__ x, const float* __restrict__ wqkv,
    const float* __restrict__ pe, const float* __restrict__ wpos,
    unsigned short* __restrict__ qu, unsigned short* __restrict__ qv,
    unsigned short* __restrict__ kb, unsigned short* __restrict__ vt,
    unsigned short* __restrict__ posb,
    const float* __restrict__ bu, const float* __restrict__ bv,
    const unsigned char* __restrict__ mk, unsigned long long* __restrict__ mwout)
{
    const int tid = threadIdx.x;
    const int bid = blockIdx.x;

    if (bid >= 512) {
        // ---- maskw role: words[(b*2048+t)*32+itg] bit s = any(mask byte)
        int base = (bid - 512) * 256 + tid;
#pragma unroll 1
        for (int idx = base; idx < 131072; idx += 32768) {
            const unsigned long long* row =
                (const unsigned long long*)(mk + (size_t)(idx >> 5) * 2048) +
                (size_t)(idx & 31) * 8;
            unsigned long long w = 0;
#pragma unroll
            for (int k = 0; k < 8; ++k) {
                unsigned long long v = row[k];
                v |= v >> 4; v |= v >> 2; v |= v >> 1;
                v &= 0x0101010101010101ull;
                w |= ((v * 0x0102040810204080ull) >> 56) << (k * 8);
            }
            mwout[idx] = w;
        }
        return;
    }

    // XCD-aware decode (assumes round-robin bid->XCD): all bx of one by-panel
    // land on xcd = by & 7. Bijective on each range (verified).
    const int role = bid >= 384 ? 1 : 0;       // 0 = QKV, 1 = pos
    int bx, by;
    if (role == 0) {
        int xcd = bid & 7, slot = bid >> 3;    // slot 0..47
        by = xcd + 8 * (slot / 12);
        bx = slot % 12;
    } else {
        int lb = bid - 384;
        int xcd = lb & 7, slot = lb >> 3;      // slot 0..15
        by = xcd + 8 * (slot >> 2);
        bx = slot & 3;
    }
    const float* A  = role ? pe : x;
    const float* Bw = role ? wpos : wqkv;
    const int M = role ? 4095 : 4096;

    __shared__ __align__(16) unsigned short As[128 * 32];
    __shared__ __align__(16) unsigned short Bs[128 * 32];

    const int lane = tid & 63;
    const int l31 = lane & 31;
    const int h = (lane >> 5) & 1;
    const int wid = tid >> 6;
    const int wm = wid >> 1, wn = wid & 1;
    const int m0 = by * 128, n0 = bx * 128;

    f32x16 acc[2][2];
#pragma unroll
    for (int mt = 0; mt < 2; ++mt)
#pragma unroll
        for (int nt = 0; nt < 2; ++nt) acc[mt][nt] = zero16();

    const int row_s = tid >> 2;
    const int q_s = tid & 3;

#pragma unroll 1
    for (int k0 = 0; k0 < 512; k0 += 32) {
        __syncthreads();
#pragma unroll
        for (int rep = 0; rep < 2; ++rep) {
            int row = row_s + rep * 64;
            int ar = m0 + row; if (ar > M - 1) ar = M - 1;
            short8 av = load8f(A, (size_t)ar * 512 + k0 + q_s * 8);
            *(short8*)((char*)As + ((row * 64 + q_s * 16) ^ ((row & 3) << 4))) = av;
            int br = n0 + row;
            short8 bv8 = load8f(Bw, (size_t)br * 512 + k0 + q_s * 8);
            *(short8*)((char*)Bs + ((row * 64 + q_s * 16) ^ ((row & 3) << 4))) = bv8;
        }
        __syncthreads();

        short8 af[2][2], bf[2][2];
#pragma unroll
        for (int mt = 0; mt < 2; ++mt)
#pragma unroll
            for (int ks = 0; ks < 2; ++ks) {
                int row = wm * 64 + mt * 32 + l31;
                af[mt][ks] = *(const short8*)((char*)As +
                    ((row * 64 + ks * 32 + h * 16) ^ ((row & 3) << 4)));
            }
#pragma unroll
        for (int nt = 0; nt < 2; ++nt)
#pragma unroll
            for (int ks = 0; ks < 2; ++ks) {
                int row = wn * 64 + nt * 32 + l31;
                bf[nt][ks] = *(const short8*)((char*)Bs +
                    ((row * 64 + ks * 32 + h * 16) ^ ((row & 3) << 4)));
            }
#pragma unroll
        for (int mt = 0; mt < 2; ++mt)
#pragma unroll
            for (int nt = 0; nt < 2; ++nt)
#pragma unroll
                for (int ks = 0; ks < 2; ++ks)
                    acc[mt][nt] = mfma_bf(af[mt][ks], bf[nt][ks], acc[mt][nt]);
    }

#pragma unroll
    for (int mt = 0; mt < 2; ++mt)
#pragma unroll
        for (int nt = 0; nt < 2; ++nt) {
            int Ncol = n0 + wn * 64 + nt * 32 + l31;
#pragma unroll
            for (int r = 0; r < 16; ++r) {
                int Mrow = m0 + wm * 64 + mt * 32 + (r & 3) + ((r >> 2) << 3) + h * 4;
                float v = acc[mt][nt][r];
                if (role == 0) {
                    int b = Mrow >> 11, t = Mrow & 2047;
                    int sec = Ncol >> 9, hd = (Ncol >> 6) & 7, dk = Ncol & 63;
                    if (sec == 0) {
                        // q_u/q_v pre-scaled into exp2 domain (C2F = 0.125*log2e)
                        size_t idx = ((size_t)((b * 8 + hd) * 2048 + t)) * 64 + dk;
                        qu[idx] = f2bf((v + bu[hd * 64 + dk]) * C2F);
                        qv[idx] = f2bf((v + bv[hd * 64 + dk]) * C2F);
                    } else if (sec == 1) {
                        kb[((size_t)((b * 8 + hd) * 2048 + t)) * 64 + dk] = f2bf(v);
                    } else {
                        // v transposed: vt[bh][dk][t]
                        vt[((size_t)((b * 8 + hd) * 64 + dk)) * 2048 + t] = f2bf(v);
                    }
                } else {
                    if (Mrow < M) {
                        int hd = Ncol >> 6, dk = Ncol & 63;
                        posb[((size_t)(hd * 4095 + Mrow)) * 64 + dk] = f2bf(v);
                    }
                }
            }
        }
}

// ---------------------------------------------------------------- fused attention
// 1024 blocks (1D), XCD-decoded: all 32 tb-blocks of one (bh, scb) land on
// xcd = (bh + 16*scb) & 7 -> K/V slice (256 KB) stays in that XCD's L2.
// 128 threads = 2 waves; wave owns 32 t-rows, block sweeps s in [sc, sc+1024).
// Swapped-operand S^T = mfma(K, Q^T); lane pair (l31,l31+32) shares a t-row.
// Scores in exp2 domain (qu/qv pre-scaled); f32 E-ring (R5-proven).
__global__ __launch_bounds__(128) void attn_kernel(
    const unsigned short* __restrict__ qup, const unsigned short* __restrict__ qvp,
    const unsigned short* __restrict__ kp,  const unsigned short* __restrict__ vtp,
    const unsigned short* __restrict__ posp,
    const unsigned long long* __restrict__ mwp,
    unsigned short* __restrict__ opart,
    float* __restrict__ mstat, float* __restrict__ lstat)
{
    // bijective XCD decode: p = (bh + 16*scb) pinned to xcd = p & 7
    const int bid = blockIdx.x;
    const int xcd = bid & 7;
    const int s_ = bid >> 3;          // 0..127
    const int tb = s_ & 31;
    const int p = xcd + 8 * (s_ >> 5); // 0..31
    const int bh = p & 15, scb = p >> 4;

    const int b = bh >> 3, head = bh & 7;
    const int t0 = tb * 64;
    const int sc = scb << 10;

    const int lane = threadIdx.x & 63;
    const int l31 = lane & 31;
    const int h = (lane >> 5) & 1;
    const int h4 = h * 4;
    const int wid = threadIdx.x >> 6;

    __shared__ __align__(16) unsigned short Kss[64 * 64];
    __shared__ __align__(16) unsigned short Vts[64 * 64];
    __shared__ __align__(16) float Ew[2 * 32 * 132];   // per-wave f32 ring [t][slot]

    const unsigned short* posg = posp + (size_t)head * 4095 * 64;
    const unsigned short* kg0 = kp + (size_t)bh * 2048 * 64;
    const unsigned short* vtg = vtp + (size_t)bh * 64 * 2048;
    const int t = t0 + wid * 32 + l31;

    // Q fragments (B-operand: col = t, k = ks*16 + h*8 + j), exp2-domain scaled
    const size_t qoff = ((size_t)bh * 2048 + t) * 64;
    short8 qu_f[4], qv_f[4];
#pragma unroll
    for (int ks = 0; ks < 4; ++ks) {
        qu_f[ks] = *(const short8*)(qup + qoff + ks * 16 + h * 8);
        qv_f[ks] = *(const short8*)(qvp + qoff + ks * 16 + h * 8);
    }

    float* ewp = Ew + (wid * 32 + l31) * 132;

    auto load_pos = [&](int c_r0, short8 (&pf)[8]) {
#pragma unroll
        for (int et = 0; et < 2; ++et) {
            int r = c_r0 + et * 32 + l31;
            r = min(r, 4094);      // clamped rows land in never-gathered slots
#pragma unroll
            for (int ks = 0; ks < 4; ++ks)
                pf[et * 4 + ks] = *(const short8*)(posg + (size_t)r * 64 + ks * 16 + h * 8);
        }
    };
    // E^T chunk: rows = 64 band slots, cols = t. Ring row shared by the h-pair
    // of THIS wave only (disjoint slot subsets qd*8 + h4 + j).
    auto e_gemm = [&](const short8 (&pf)[8], int slotb) {
#pragma unroll
        for (int et = 0; et < 2; ++et) {
            f32x16 ea = zero16();
#pragma unroll
            for (int ks = 0; ks < 4; ++ks)
                ea = mfma_bf(pf[et * 4 + ks], qv_f[ks], ea);
#pragma unroll
            for (int qd = 0; qd < 4; ++qd) {
                f32x4 w;
                w[0] = ea[qd * 4 + 0]; w[1] = ea[qd * 4 + 1];
                w[2] = ea[qd * 4 + 2]; w[3] = ea[qd * 4 + 3];
                *(f32x4*)(ewp + slotb + et * 32 + qd * 8 + h4) = w;
            }
        }
    };

    // 64-aligned ring origin (R5/R8-verified coverage)
    const int c0 = sc + 1984 - t0;
    {
        short8 pf0[8];
        load_pos(c0, pf0);      e_gemm(pf0, c0 & 127);
        load_pos(c0 + 64, pf0); e_gemm(pf0, (c0 + 64) & 127);
    }

    float m = -3.0e38f, lsum = 0.0f;
    f32x16 o_acc[2];
    o_acc[0] = zero16(); o_acc[1] = zero16();

    const int st_row = threadIdx.x >> 3;     // 0..15 (+16 per rep)
    const int st_q = threadIdx.x & 7;
    const size_t mw_base = ((size_t)(b * 2048 + t)) * 32 + (sc >> 6);

#pragma unroll 1
    for (int it = 0; it < 16; ++it) {
        const int s0a = sc + it * 64;
        __syncthreads();                  // prior tile reads complete (all waves)
        // ---- stage K[s][dk] and V^T[dk][s] tiles (swizzled ds_write_b128)
#pragma unroll
        for (int rep = 0; rep < 4; ++rep) {
            int row = st_row + rep * 16;
            int off = (row * 128 + st_q * 16) ^ ((row & 7) << 4);
            *(short8*)((char*)Kss + off) =
                *(const short8*)(kg0 + ((size_t)(s0a + row)) * 64 + st_q * 8);
            *(short8*)((char*)Vts + off) =
                *(const short8*)(vtg + (size_t)row * 2048 + s0a + st_q * 8);
        }
        short8 pf[8];
        if (it < 15) load_pos(c0 + 128 + 64 * it, pf);
        unsigned long long mw = mwp[mw_base + it];
        __syncthreads();                  // staged tiles visible

        // ---- S^T = K . Qu^T (already exp2-domain scaled via qu)
        f32x16 sacc[2];
        sacc[0] = zero16(); sacc[1] = zero16();
#pragma unroll
        for (int st2 = 0; st2 < 2; ++st2)
#pragma unroll
            for (int ks = 0; ks < 4; ++ks) {
                int row = st2 * 32 + l31;
                short8 a = *(const short8*)((char*)Kss +
                    ((row * 128 + ks * 32 + h * 16) ^ ((row & 7) << 4)));
                sacc[st2] = mfma_bf(a, qu_f[ks], sacc[st2]);
            }

        // ---- add banded BD from ring (both terms pre-scaled), mask
        const int sb = s0a - t + 2047;
        float sv[32];
#pragma unroll
        for (int st2 = 0; st2 < 2; ++st2)
#pragma unroll
            for (int r = 0; r < 16; ++r) {
                int slot = (sb + st2 * 32 + (r & 3) + ((r >> 2) << 3) + h4) & 127;
                sv[st2 * 16 + r] = sacc[st2][r] + ewp[slot];
            }
        if (__any(mw != 0ull)) {
#pragma unroll
            for (int st2 = 0; st2 < 2; ++st2)
#pragma unroll
                for (int r = 0; r < 16; ++r) {
                    int s_loc = st2 * 32 + (r & 3) + ((r >> 2) << 3) + h4;
                    if ((mw >> s_loc) & 1ull)
                        sv[st2 * 16 + r] = sacc[st2][r] - MOFF;
                }
        }

        // ---- online softmax (exp2 domain, bare v_exp), pair-combined via ^32
        float mx = sv[0];
#pragma unroll
        for (int i = 1; i < 32; ++i) mx = fmaxf(mx, sv[i]);
        mx = fmaxf(mx, __shfl_xor(mx, 32));
        float mnew = fmaxf(m, mx);
        float alpha = exp2v(m - mnew);
        m = mnew;
        float psum = 0.0f;
#pragma unroll
        for (int i = 0; i < 32; ++i) { sv[i] = exp2v(sv[i] - mnew); psum += sv[i]; }
        psum += __shfl_xor(psum, 32);
        lsum = lsum * alpha + psum;
        o_acc[0] = o_acc[0] * alpha;
        o_acc[1] = o_acc[1] * alpha;

        // ---- pack P^T into B-fragments (cvt_pk pairs + symmetric exchange)
        short8 pfrag[4];
#pragma unroll
        for (int st2 = 0; st2 < 2; ++st2) {
            unsigned int X[8];
#pragma unroll
            for (int qd = 0; qd < 4; ++qd) {
                X[qd * 2 + 0] = cvt2bf(sv[st2 * 16 + qd * 4 + 0], sv[st2 * 16 + qd * 4 + 1]);
                X[qd * 2 + 1] = cvt2bf(sv[st2 * 16 + qd * 4 + 2], sv[st2 * 16 + qd * 4 + 3]);
            }
#pragma unroll
            for (int f = 0; f < 2; ++f) {
                unsigned int a0 = X[4 * f + 0], a1 = X[4 * f + 1];
                unsigned int b0 = X[4 * f + 2], b1 = X[4 * f + 3];
                unsigned int sa0 = (unsigned int)__shfl_xor((int)a0, 32);
                unsigned int sa1 = (unsigned int)__shfl_xor((int)a1, 32);
                unsigned int sb0 = (unsigned int)__shfl_xor((int)b0, 32);
                unsigned int sb1 = (unsigned int)__shfl_xor((int)b1, 32);
                union { unsigned int u[4]; short8 s8; } uu;
                uu.u[0] = h ? sb0 : a0;
                uu.u[1] = h ? sb1 : a1;
                uu.u[2] = h ? b0 : sa0;
                uu.u[3] = h ? b1 : sa1;
                pfrag[st2 * 2 + f] = uu.s8;
            }
        }

        // ---- O^T += V^T . P^T
#pragma unroll
        for (int dkt = 0; dkt < 2; ++dkt)
#pragma unroll
            for (int f = 0; f < 4; ++f) {
                int row = dkt * 32 + l31;
                short8 a = *(const short8*)((char*)Vts +
                    ((row * 128 + f * 32 + h * 16) ^ ((row & 7) << 4)));
                o_acc[dkt] = mfma_bf(a, pfrag[f], o_acc[dkt]);
            }

        // ---- produce next ring chunk (wave-private; overwrites consumed slots)
        if (it < 15) e_gemm(pf, (c0 + 128 + 64 * it) & 127);
    }

    // ---- epilogue: normalized bf16 partials + stats (log2-domain m)
    float inv = 1.0f / lsum;
    if (m <= -9.0e4f) inv = 0.0f;
    size_t obase = (((size_t)scb * 16 + bh) * 2048 + t) * 64;
#pragma unroll
    for (int dkt = 0; dkt < 2; ++dkt)
#pragma unroll
        for (int qd = 0; qd < 4; ++qd) {
            int dk0 = dkt * 32 + qd * 8 + h4;
            uint2v u;
            u.x = cvt2bf(o_acc[dkt][qd * 4 + 0] * inv, o_acc[dkt][qd * 4 + 1] * inv);
            u.y = cvt2bf(o_acc[dkt][qd * 4 + 2] * inv, o_acc[dkt][qd * 4 + 3] * inv);
            *(uint2v*)(opart + obase + dk0) = u;
        }
    if (h == 0) {
        size_t sidx = ((size_t)scb * 16 + bh) * 2048 + t;
        mstat[sidx] = m;
        lstat[sidx] = lsum;
    }
}

// ---------------------------------------------------------------- back
// out-GEMM (M=4096, N=512) with 2-way combine fused into A staging.
// 128 blocks 1D, XCD-decoded (panel by pinned to xcd = by&7).
__global__ __launch_bounds__(256) void back_kernel(
    const unsigned short* __restrict__ opart, const float* __restrict__ wout,
    const float* __restrict__ mstat, const float* __restrict__ lstat,
    float* __restrict__ o_f)
{
    __shared__ __align__(16) unsigned short As[128 * 32];
    __shared__ __align__(16) unsigned short Bs[128 * 32];

    const int bid = blockIdx.x;
    const int xcd = bid & 7, slot = bid >> 3;   // slot 0..15
    const int by = xcd + 8 * (slot >> 2);
    const int bx = slot & 3;

    const int tid = threadIdx.x;
    const int lane = tid & 63;
    const int l31 = lane & 31;
    const int h = (lane >> 5) & 1;
    const int wid = tid >> 6;
    const int wm = wid >> 1, wn = wid & 1;
    const int m0 = by * 128, n0 = bx * 128;

    f32x16 acc[2][2];
#pragma unroll
    for (int mt = 0; mt < 2; ++mt)
#pragma unroll
        for (int nt = 0; nt < 2; ++nt) acc[mt][nt] = zero16();

    const int row_s = tid >> 2;
    const int q_s = tid & 3;

#pragma unroll 1
    for (int k0 = 0; k0 < 512; k0 += 32) {
        __syncthreads();
#pragma unroll
        for (int rep = 0; rep < 2; ++rep) {
            int row = row_s + rep * 64;
            int ar = m0 + row;
            // ---- combine 2 normalized partials into the A operand
            int t_ = ar & 2047, b_ = ar >> 11;
            int c = k0 + q_s * 8;
            int head = c >> 6, dk0 = c & 63;
            int row2 = (b_ * 8 + head) * 2048 + t_;
            float m0s = mstat[row2], m1s = mstat[32768 + row2];
            float l0s = lstat[row2], l1s = lstat[32768 + row2];
            float Mx = fmaxf(m0s, m1s);
            float w0 = exp2v(m0s - Mx) * l0s, w1 = exp2v(m1s - Mx) * l1s;
            float den = w0 + w1;
            float inv = (den > 0.0f && Mx > -9.0e4f) ? 1.0f / den : 0.0f;
            w0 *= inv; w1 *= inv;
            short8 p0 = *(const short8*)(opart + (size_t)row2 * 64 + dk0);
            short8 p1 = *(const short8*)(opart + ((size_t)32768 + row2) * 64 + dk0);
            union { unsigned int u[4]; short8 s; } r;
#pragma unroll
            for (int j = 0; j < 4; ++j) {
                float lo = w0 * bf2f((unsigned short)p0[2 * j]) +
                           w1 * bf2f((unsigned short)p1[2 * j]);
                float hi = w0 * bf2f((unsigned short)p0[2 * j + 1]) +
                           w1 * bf2f((unsigned short)p1[2 * j + 1]);
                r.u[j] = cvt2bf(lo, hi);
            }
            *(short8*)((char*)As + ((row * 64 + q_s * 16) ^ ((row & 3) << 4))) = r.s;
            int br = n0 + row;
            short8 bv8 = load8f(wout, (size_t)br * 512 + k0 + q_s * 8);
            *(short8*)((char*)Bs + ((row * 64 + q_s * 16) ^ ((row & 3) << 4))) = bv8;
        }
        __syncthreads();

        short8 af[2][2], bf[2][2];
#pragma unroll
        for (int mt = 0; mt < 2; ++mt)
#pragma unroll
            for (int ks = 0; ks < 2; ++ks) {
                int row = wm * 64 + mt * 32 + l31;
                af[mt][ks] = *(const short8*)((char*)As +
                    ((row * 64 + ks * 32 + h * 16) ^ ((row & 3) << 4)));
            }
#pragma unroll
        for (int nt = 0; nt < 2; ++nt)
#pragma unroll
            for (int ks = 0; ks < 2; ++ks) {
                int row = wn * 64 + nt * 32 + l31;
                bf[nt][ks] = *(const short8*)((char*)Bs +
                    ((row * 64 + ks * 32 + h * 16) ^ ((row & 3) << 4)));
            }
#pragma unroll
        for (int mt = 0; mt < 2; ++mt)
#pragma unroll
            for (int nt = 0; nt < 2; ++nt)
#pragma unroll
                for (int ks = 0; ks < 2; ++ks)
                    acc[mt][nt] = mfma_bf(af[mt][ks], bf[nt][ks], acc[mt][nt]);
    }

#pragma unroll
    for (int mt = 0; mt < 2; ++mt)
#pragma unroll
        for (int nt = 0; nt < 2; ++nt) {
            int Ncol = n0 + wn * 64 + nt * 32 + l31;
#pragma unroll
            for (int r = 0; r < 16; ++r) {
                int Mrow = m0 + wm * 64 + mt * 32 + (r & 3) + ((r >> 2) << 3) + h * 4;
                o_f[(size_t)Mrow * 512 + Ncol] = acc[mt][nt][r];
            }
        }
}

// ---------------------------------------------------------------- host
extern "C" void kernel_launch(void* const* d_in, const int* in_sizes, int n_in,
                              void* d_out, int out_size, void* d_ws, size_t ws_size,
                              hipStream_t stream) {
    const float* x    = (const float*)d_in[0];
    const float* pe   = (const float*)d_in[1];
    const unsigned char* mask = (const unsigned char*)d_in[2];
    const float* wqkv = (const float*)d_in[3];
    const float* wpos = (const float*)d_in[4];
    const float* wout = (const float*)d_in[5];
    const float* bu   = (const float*)d_in[6];
    const float* bv   = (const float*)d_in[7];
    float* out = (float*)d_out;

    char* ws = (char*)d_ws;
    unsigned short* qu    = (unsigned short*)(ws + 0);
    unsigned short* qv    = (unsigned short*)(ws + 4194304);
    unsigned short* kb    = (unsigned short*)(ws + 8388608);
    unsigned short* vt    = (unsigned short*)(ws + 12582912);
    unsigned short* posb  = (unsigned short*)(ws + 16777216);   // 4,193,280 B
    unsigned long long* maskw = (unsigned long long*)(ws + 20971520); // 1 MB
    unsigned short* opart = (unsigned short*)(ws + 22020096);   // 8,388,608 B
    float* mstat          = (float*)(ws + 30408704);            // 262,144 B
    float* lstat          = (float*)(ws + 30670848);            // 262,144 B
    // total ws use ~31 MB, no overlaps

    front_kernel<<<640, 256, 0, stream>>>(
        x, wqkv, pe, wpos, qu, qv, kb, vt, posb, bu, bv, mask, maskw);
    attn_kernel<<<1024, 128, 0, stream>>>(
        qu, qv, kb, vt, posb, maskw, opart, mstat, lstat);
    back_kernel<<<128, 256, 0, stream>>>(
        opart, wout, mstat, lstat, out);
}

// Round 17
// 131.246 us; speedup vs baseline: 1.1687x; 1.0595x over previous
//
#include <hip/hip_runtime.h>
#include <hip/hip_bf16.h>

// ConformerAttention on MI355X (gfx950)
// B=2 T=2048 D=512 NH=8 DK=64 P=4095
// rel_shift identity: scores_bd[t,s] = q_v[t] . pos[s - t + 2047]
// -> banded GEMM with rolling 128-slot f32 ring (each band column computed once).
// R17 = R16 (best: 139.1us; attn 87.3 w/ XCD swizzle) + BK=64 in front/back
// GEMMs: 8 K-steps instead of 16 (half the barriers), 4 MFMA k-slices per step.
// 128x64 bf16 tiles reuse attn's proven 128B-row swizzle. attn unchanged.

typedef __attribute__((ext_vector_type(8))) short short8;
typedef __attribute__((ext_vector_type(16))) float f32x16;
typedef __attribute__((ext_vector_type(4))) float f32x4;
typedef __attribute__((ext_vector_type(2))) unsigned int uint2v;

#define C2F 0.18033688011112043f   // 0.125 * log2(e)
#define MOFF 144269.504088896f     // 100000 * log2(e)

static __device__ __forceinline__ unsigned short f2bf(float x) {
    unsigned int u = __builtin_bit_cast(unsigned int, x);
    u += 0x7FFFu + ((u >> 16) & 1u);   // RNE
    return (unsigned short)(u >> 16);
}
static __device__ __forceinline__ unsigned int cvt2bf(float lo, float hi) {
    // v_cvt_pk_bf16_f32 via the official intrinsic (RNE, matches f2bf)
    __hip_bfloat162 h = __float22bfloat162_rn(make_float2(lo, hi));
    unsigned int r;
    __builtin_memcpy(&r, &h, 4);
    return r;
}
static __device__ __forceinline__ float exp2v(float x) {
    return __builtin_amdgcn_exp2f(x);   // bare v_exp_f32
}
static __device__ __forceinline__ float bf2f(unsigned short u) {
    return __builtin_bit_cast(float, (unsigned int)u << 16);
}
static __device__ __forceinline__ f32x16 zero16() {
    f32x16 v;
#pragma unroll
    for (int i = 0; i < 16; ++i) v[i] = 0.0f;
    return v;
}
static __device__ __forceinline__ f32x16 mfma_bf(short8 a, short8 b, f32x16 c) {
    return __builtin_amdgcn_mfma_f32_32x32x16_bf16(a, b, c, 0, 0, 0);
}
static __device__ __forceinline__ short8 load8f(const float* base, size_t eoff) {
    const float4* p = (const float4*)(base + eoff);
    float4 a = p[0], b = p[1];
    union { unsigned int u[4]; short8 s; } r;
    r.u[0] = cvt2bf(a.x, a.y);
    r.u[1] = cvt2bf(a.z, a.w);
    r.u[2] = cvt2bf(b.x, b.y);
    r.u[3] = cvt2bf(b.z, b.w);
    return r.s;
}

// ---------------------------------------------------------------- front
// 640 blocks: [0,384) QKV GEMM (M=4096,N=1536), [384,512) pos GEMM (M=4095,
// N=512), [512,640) maskw. XCD swizzle: panel by pinned to xcd = by&7.
// GEMM: 128x128 tile, 4 waves, BK=64 (8 K-steps), 128x64 swizzled LDS tiles.
__global__ __launch_bounds__(256) void front_kernel(
    const float* __restrict__ x, const float* __restrict__ wqkv,
    const float* __restrict__ pe, const float* __restrict__ wpos,
    unsigned short* __restrict__ qu, unsigned short* __restrict__ qv,
    unsigned short* __restrict__ kb, unsigned short* __restrict__ vt,
    unsigned short* __restrict__ posb,
    const float* __restrict__ bu, const float* __restrict__ bv,
    const unsigned char* __restrict__ mk, unsigned long long* __restrict__ mwout)
{
    const int tid = threadIdx.x;
    const int bid = blockIdx.x;

    if (bid >= 512) {
        // ---- maskw role: words[(b*2048+t)*32+itg] bit s = any(mask byte)
        int base = (bid - 512) * 256 + tid;
#pragma unroll 1
        for (int idx = base; idx < 131072; idx += 32768) {
            const unsigned long long* row =
                (const unsigned long long*)(mk + (size_t)(idx >> 5) * 2048) +
                (size_t)(idx & 31) * 8;
            unsigned long long w = 0;
#pragma unroll
            for (int k = 0; k < 8; ++k) {
                unsigned long long v = row[k];
                v |= v >> 4; v |= v >> 2; v |= v >> 1;
                v &= 0x0101010101010101ull;
                w |= ((v * 0x0102040810204080ull) >> 56) << (k * 8);
            }
            mwout[idx] = w;
        }
        return;
    }

    // XCD-aware decode: all bx of one by-panel land on xcd = by & 7.
    const int role = bid >= 384 ? 1 : 0;       // 0 = QKV, 1 = pos
    int bx, by;
    if (role == 0) {
        int xcd = bid & 7, slot = bid >> 3;    // slot 0..47
        by = xcd + 8 * (slot / 12);
        bx = slot % 12;
    } else {
        int lb = bid - 384;
        int xcd = lb & 7, slot = lb >> 3;      // slot 0..15
        by = xcd + 8 * (slot >> 2);
        bx = slot & 3;
    }
    const float* A  = role ? pe : x;
    const float* Bw = role ? wpos : wqkv;
    const int M = role ? 4095 : 4096;

    __shared__ __align__(16) unsigned short As[128 * 64];
    __shared__ __align__(16) unsigned short Bs[128 * 64];

    const int lane = tid & 63;
    const int l31 = lane & 31;
    const int h = (lane >> 5) & 1;
    const int wid = tid >> 6;
    const int wm = wid >> 1, wn = wid & 1;
    const int m0 = by * 128, n0 = bx * 128;

    f32x16 acc[2][2];
#pragma unroll
    for (int mt = 0; mt < 2; ++mt)
#pragma unroll
        for (int nt = 0; nt < 2; ++nt) acc[mt][nt] = zero16();

    const int st_row = tid >> 3;   // 0..31 (+32 per rep)
    const int st_q = tid & 7;

#pragma unroll 1
    for (int k0 = 0; k0 < 512; k0 += 64) {
        __syncthreads();
#pragma unroll
        for (int rep = 0; rep < 4; ++rep) {
            int row = st_row + rep * 32;
            int ar = m0 + row; if (ar > M - 1) ar = M - 1;
            int off = (row * 128 + st_q * 16) ^ ((row & 7) << 4);
            *(short8*)((char*)As + off) =
                load8f(A, (size_t)ar * 512 + k0 + st_q * 8);
            int br = n0 + row;
            *(short8*)((char*)Bs + off) =
                load8f(Bw, (size_t)br * 512 + k0 + st_q * 8);
        }
        __syncthreads();

        const int rowa0 = wm * 64 + l31, rowa1 = wm * 64 + 32 + l31;
        const int rowb0 = wn * 64 + l31, rowb1 = wn * 64 + 32 + l31;
#pragma unroll
        for (int ks = 0; ks < 4; ++ks) {
            short8 a0 = *(const short8*)((char*)As +
                ((rowa0 * 128 + ks * 32 + h * 16) ^ ((rowa0 & 7) << 4)));
            short8 a1 = *(const short8*)((char*)As +
                ((rowa1 * 128 + ks * 32 + h * 16) ^ ((rowa1 & 7) << 4)));
            short8 b0 = *(const short8*)((char*)Bs +
                ((rowb0 * 128 + ks * 32 + h * 16) ^ ((rowb0 & 7) << 4)));
            short8 b1 = *(const short8*)((char*)Bs +
                ((rowb1 * 128 + ks * 32 + h * 16) ^ ((rowb1 & 7) << 4)));
            acc[0][0] = mfma_bf(a0, b0, acc[0][0]);
            acc[0][1] = mfma_bf(a0, b1, acc[0][1]);
            acc[1][0] = mfma_bf(a1, b0, acc[1][0]);
            acc[1][1] = mfma_bf(a1, b1, acc[1][1]);
        }
    }

#pragma unroll
    for (int mt = 0; mt < 2; ++mt)
#pragma unroll
        for (int nt = 0; nt < 2; ++nt) {
            int Ncol = n0 + wn * 64 + nt * 32 + l31;
#pragma unroll
            for (int r = 0; r < 16; ++r) {
                int Mrow = m0 + wm * 64 + mt * 32 + (r & 3) + ((r >> 2) << 3) + h * 4;
                float v = acc[mt][nt][r];
                if (role == 0) {
                    int b = Mrow >> 11, t = Mrow & 2047;
                    int sec = Ncol >> 9, hd = (Ncol >> 6) & 7, dk = Ncol & 63;
                    if (sec == 0) {
                        // q_u/q_v pre-scaled into exp2 domain (C2F = 0.125*log2e)
                        size_t idx = ((size_t)((b * 8 + hd) * 2048 + t)) * 64 + dk;
                        qu[idx] = f2bf((v + bu[hd * 64 + dk]) * C2F);
                        qv[idx] = f2bf((v + bv[hd * 64 + dk]) * C2F);
                    } else if (sec == 1) {
                        kb[((size_t)((b * 8 + hd) * 2048 + t)) * 64 + dk] = f2bf(v);
                    } else {
                        // v transposed: vt[bh][dk][t]
                        vt[((size_t)((b * 8 + hd) * 64 + dk)) * 2048 + t] = f2bf(v);
                    }
                } else {
                    if (Mrow < M) {
                        int hd = Ncol >> 6, dk = Ncol & 63;
                        posb[((size_t)(hd * 4095 + Mrow)) * 64 + dk] = f2bf(v);
                    }
                }
            }
        }
}

// ---------------------------------------------------------------- fused attention
// 1024 blocks (1D), XCD-decoded: all 32 tb-blocks of one (bh, scb) land on
// xcd = (bh + 16*scb) & 7 -> K/V slice (256 KB) stays in that XCD's L2.
// 128 threads = 2 waves; wave owns 32 t-rows, block sweeps s in [sc, sc+1024).
// Swapped-operand S^T = mfma(K, Q^T); lane pair (l31,l31+32) shares a t-row.
// Scores in exp2 domain (qu/qv pre-scaled); f32 E-ring (R5-proven). UNCHANGED.
__global__ __launch_bounds__(128) void attn_kernel(
    const unsigned short* __restrict__ qup, const unsigned short* __restrict__ qvp,
    const unsigned short* __restrict__ kp,  const unsigned short* __restrict__ vtp,
    const unsigned short* __restrict__ posp,
    const unsigned long long* __restrict__ mwp,
    unsigned short* __restrict__ opart,
    float* __restrict__ mstat, float* __restrict__ lstat)
{
    // bijective XCD decode: p = (bh + 16*scb) pinned to xcd = p & 7
    const int bid = blockIdx.x;
    const int xcd = bid & 7;
    const int s_ = bid >> 3;          // 0..127
    const int tb = s_ & 31;
    const int p = xcd + 8 * (s_ >> 5); // 0..31
    const int bh = p & 15, scb = p >> 4;

    const int b = bh >> 3, head = bh & 7;
    const int t0 = tb * 64;
    const int sc = scb << 10;

    const int lane = threadIdx.x & 63;
    const int l31 = lane & 31;
    const int h = (lane >> 5) & 1;
    const int h4 = h * 4;
    const int wid = threadIdx.x >> 6;

    __shared__ __align__(16) unsigned short Kss[64 * 64];
    __shared__ __align__(16) unsigned short Vts[64 * 64];
    __shared__ __align__(16) float Ew[2 * 32 * 132];   // per-wave f32 ring [t][slot]

    const unsigned short* posg = posp + (size_t)head * 4095 * 64;
    const unsigned short* kg0 = kp + (size_t)bh * 2048 * 64;
    const unsigned short* vtg = vtp + (size_t)bh * 64 * 2048;
    const int t = t0 + wid * 32 + l31;

    // Q fragments (B-operand: col = t, k = ks*16 + h*8 + j), exp2-domain scaled
    const size_t qoff = ((size_t)bh * 2048 + t) * 64;
    short8 qu_f[4], qv_f[4];
#pragma unroll
    for (int ks = 0; ks < 4; ++ks) {
        qu_f[ks] = *(const short8*)(qup + qoff + ks * 16 + h * 8);
        qv_f[ks] = *(const short8*)(qvp + qoff + ks * 16 + h * 8);
    }

    float* ewp = Ew + (wid * 32 + l31) * 132;

    auto load_pos = [&](int c_r0, short8 (&pf)[8]) {
#pragma unroll
        for (int et = 0; et < 2; ++et) {
            int r = c_r0 + et * 32 + l31;
            r = min(r, 4094);      // clamped rows land in never-gathered slots
#pragma unroll
            for (int ks = 0; ks < 4; ++ks)
                pf[et * 4 + ks] = *(const short8*)(posg + (size_t)r * 64 + ks * 16 + h * 8);
        }
    };
    // E^T chunk: rows = 64 band slots, cols = t. Ring row shared by the h-pair
    // of THIS wave only (disjoint slot subsets qd*8 + h4 + j).
    auto e_gemm = [&](const short8 (&pf)[8], int slotb) {
#pragma unroll
        for (int et = 0; et < 2; ++et) {
            f32x16 ea = zero16();
#pragma unroll
            for (int ks = 0; ks < 4; ++ks)
                ea = mfma_bf(pf[et * 4 + ks], qv_f[ks], ea);
#pragma unroll
            for (int qd = 0; qd < 4; ++qd) {
                f32x4 w;
                w[0] = ea[qd * 4 + 0]; w[1] = ea[qd * 4 + 1];
                w[2] = ea[qd * 4 + 2]; w[3] = ea[qd * 4 + 3];
                *(f32x4*)(ewp + slotb + et * 32 + qd * 8 + h4) = w;
            }
        }
    };

    // 64-aligned ring origin (R5/R8-verified coverage)
    const int c0 = sc + 1984 - t0;
    {
        short8 pf0[8];
        load_pos(c0, pf0);      e_gemm(pf0, c0 & 127);
        load_pos(c0 + 64, pf0); e_gemm(pf0, (c0 + 64) & 127);
    }

    float m = -3.0e38f, lsum = 0.0f;
    f32x16 o_acc[2];
    o_acc[0] = zero16(); o_acc[1] = zero16();

    const int st_row = threadIdx.x >> 3;     // 0..15 (+16 per rep)
    const int st_q = threadIdx.x & 7;
    const size_t mw_base = ((size_t)(b * 2048 + t)) * 32 + (sc >> 6);

#pragma unroll 1
    for (int it = 0; it < 16; ++it) {
        const int s0a = sc + it * 64;
        __syncthreads();                  // prior tile reads complete (all waves)
        // ---- stage K[s][dk] and V^T[dk][s] tiles (swizzled ds_write_b128)
#pragma unroll
        for (int rep = 0; rep < 4; ++rep) {
            int row = st_row + rep * 16;
            int off = (row * 128 + st_q * 16) ^ ((row & 7) << 4);
            *(short8*)((char*)Kss + off) =
                *(const short8*)(kg0 + ((size_t)(s0a + row)) * 64 + st_q * 8);
            *(short8*)((char*)Vts + off) =
                *(const short8*)(vtg + (size_t)row * 2048 + s0a + st_q * 8);
        }
        short8 pf[8];
        if (it < 15) load_pos(c0 + 128 + 64 * it, pf);
        unsigned long long mw = mwp[mw_base + it];
        __syncthreads();                  // staged tiles visible

        // ---- S^T = K . Qu^T (already exp2-domain scaled via qu)
        f32x16 sacc[2];
        sacc[0] = zero16(); sacc[1] = zero16();
#pragma unroll
        for (int st2 = 0; st2 < 2; ++st2)
#pragma unroll
            for (int ks = 0; ks < 4; ++ks) {
                int row = st2 * 32 + l31;
                short8 a = *(const short8*)((char*)Kss +
                    ((row * 128 + ks * 32 + h * 16) ^ ((row & 7) << 4)));
                sacc[st2] = mfma_bf(a, qu_f[ks], sacc[st2]);
            }

        // ---- add banded BD from ring (both terms pre-scaled), mask
        const int sb = s0a - t + 2047;
        float sv[32];
#pragma unroll
        for (int st2 = 0; st2 < 2; ++st2)
#pragma unroll
            for (int r = 0; r < 16; ++r) {
                int slot = (sb + st2 * 32 + (r & 3) + ((r >> 2) << 3) + h4) & 127;
                sv[st2 * 16 + r] = sacc[st2][r] + ewp[slot];
            }
        if (__any(mw != 0ull)) {
#pragma unroll
            for (int st2 = 0; st2 < 2; ++st2)
#pragma unroll
                for (int r = 0; r < 16; ++r) {
                    int s_loc = st2 * 32 + (r & 3) + ((r >> 2) << 3) + h4;
                    if ((mw >> s_loc) & 1ull)
                        sv[st2 * 16 + r] = sacc[st2][r] - MOFF;
                }
        }

        // ---- online softmax (exp2 domain, bare v_exp), pair-combined via ^32
        float mx = sv[0];
#pragma unroll
        for (int i = 1; i < 32; ++i) mx = fmaxf(mx, sv[i]);
        mx = fmaxf(mx, __shfl_xor(mx, 32));
        float mnew = fmaxf(m, mx);
        float alpha = exp2v(m - mnew);
        m = mnew;
        float psum = 0.0f;
#pragma unroll
        for (int i = 0; i < 32; ++i) { sv[i] = exp2v(sv[i] - mnew); psum += sv[i]; }
        psum += __shfl_xor(psum, 32);
        lsum = lsum * alpha + psum;
        o_acc[0] = o_acc[0] * alpha;
        o_acc[1] = o_acc[1] * alpha;

        // ---- pack P^T into B-fragments (cvt_pk pairs + symmetric exchange)
        short8 pfrag[4];
#pragma unroll
        for (int st2 = 0; st2 < 2; ++st2) {
            unsigned int X[8];
#pragma unroll
            for (int qd = 0; qd < 4; ++qd) {
                X[qd * 2 + 0] = cvt2bf(sv[st2 * 16 + qd * 4 + 0], sv[st2 * 16 + qd * 4 + 1]);
                X[qd * 2 + 1] = cvt2bf(sv[st2 * 16 + qd * 4 + 2], sv[st2 * 16 + qd * 4 + 3]);
            }
#pragma unroll
            for (int f = 0; f < 2; ++f) {
                unsigned int a0 = X[4 * f + 0], a1 = X[4 * f + 1];
                unsigned int b0 = X[4 * f + 2], b1 = X[4 * f + 3];
                unsigned int sa0 = (unsigned int)__shfl_xor((int)a0, 32);
                unsigned int sa1 = (unsigned int)__shfl_xor((int)a1, 32);
                unsigned int sb0 = (unsigned int)__shfl_xor((int)b0, 32);
                unsigned int sb1 = (unsigned int)__shfl_xor((int)b1, 32);
                union { unsigned int u[4]; short8 s8; } uu;
                uu.u[0] = h ? sb0 : a0;
                uu.u[1] = h ? sb1 : a1;
                uu.u[2] = h ? b0 : sa0;
                uu.u[3] = h ? b1 : sa1;
                pfrag[st2 * 2 + f] = uu.s8;
            }
        }

        // ---- O^T += V^T . P^T
#pragma unroll
        for (int dkt = 0; dkt < 2; ++dkt)
#pragma unroll
            for (int f = 0; f < 4; ++f) {
                int row = dkt * 32 + l31;
                short8 a = *(const short8*)((char*)Vts +
                    ((row * 128 + f * 32 + h * 16) ^ ((row & 7) << 4)));
                o_acc[dkt] = mfma_bf(a, pfrag[f], o_acc[dkt]);
            }

        // ---- produce next ring chunk (wave-private; overwrites consumed slots)
        if (it < 15) e_gemm(pf, (c0 + 128 + 64 * it) & 127);
    }

    // ---- epilogue: normalized bf16 partials + stats (log2-domain m)
    float inv = 1.0f / lsum;
    if (m <= -9.0e4f) inv = 0.0f;
    size_t obase = (((size_t)scb * 16 + bh) * 2048 + t) * 64;
#pragma unroll
    for (int dkt = 0; dkt < 2; ++dkt)
#pragma unroll
        for (int qd = 0; qd < 4; ++qd) {
            int dk0 = dkt * 32 + qd * 8 + h4;
            uint2v u;
            u.x = cvt2bf(o_acc[dkt][qd * 4 + 0] * inv, o_acc[dkt][qd * 4 + 1] * inv);
            u.y = cvt2bf(o_acc[dkt][qd * 4 + 2] * inv, o_acc[dkt][qd * 4 + 3] * inv);
            *(uint2v*)(opart + obase + dk0) = u;
        }
    if (h == 0) {
        size_t sidx = ((size_t)scb * 16 + bh) * 2048 + t;
        mstat[sidx] = m;
        lstat[sidx] = lsum;
    }
}

// ---------------------------------------------------------------- back
// out-GEMM (M=4096, N=512), BK=64, with 2-way combine fused into A staging.
// 128 blocks 1D, XCD-decoded (panel by pinned to xcd = by&7).
__global__ __launch_bounds__(256) void back_kernel(
    const unsigned short* __restrict__ opart, const float* __restrict__ wout,
    const float* __restrict__ mstat, const float* __restrict__ lstat,
    float* __restrict__ o_f)
{
    __shared__ __align__(16) unsigned short As[128 * 64];
    __shared__ __align__(16) unsigned short Bs[128 * 64];

    const int bid = blockIdx.x;
    const int xcd = bid & 7, slot = bid >> 3;   // slot 0..15
    const int by = xcd + 8 * (slot >> 2);
    const int bx = slot & 3;

    const int tid = threadIdx.x;
    const int lane = tid & 63;
    const int l31 = lane & 31;
    const int h = (lane >> 5) & 1;
    const int wid = tid >> 6;
    const int wm = wid >> 1, wn = wid & 1;
    const int m0 = by * 128, n0 = bx * 128;

    f32x16 acc[2][2];
#pragma unroll
    for (int mt = 0; mt < 2; ++mt)
#pragma unroll
        for (int nt = 0; nt < 2; ++nt) acc[mt][nt] = zero16();

    const int st_row = tid >> 3;   // 0..31 (+32 per rep)
    const int st_q = tid & 7;

#pragma unroll 1
    for (int k0 = 0; k0 < 512; k0 += 64) {
        __syncthreads();
        const int head = k0 >> 6;   // one head per K-step
#pragma unroll
        for (int rep = 0; rep < 4; ++rep) {
            int row = st_row + rep * 32;
            int ar = m0 + row;
            // ---- combine 2 normalized partials into the A operand
            int t_ = ar & 2047, b_ = ar >> 11;
            int dk0 = st_q * 8;
            int row2 = (b_ * 8 + head) * 2048 + t_;
            float m0s = mstat[row2], m1s = mstat[32768 + row2];
            float l0s = lstat[row2], l1s = lstat[32768 + row2];
            float Mx = fmaxf(m0s, m1s);
            float w0 = exp2v(m0s - Mx) * l0s, w1 = exp2v(m1s - Mx) * l1s;
            float den = w0 + w1;
            float inv = (den > 0.0f && Mx > -9.0e4f) ? 1.0f / den : 0.0f;
            w0 *= inv; w1 *= inv;
            short8 p0 = *(const short8*)(opart + (size_t)row2 * 64 + dk0);
            short8 p1 = *(const short8*)(opart + ((size_t)32768 + row2) * 64 + dk0);
            union { unsigned int u[4]; short8 s; } r;
#pragma unroll
            for (int j = 0; j < 4; ++j) {
                float lo = w0 * bf2f((unsigned short)p0[2 * j]) +
                           w1 * bf2f((unsigned short)p1[2 * j]);
                float hi = w0 * bf2f((unsigned short)p0[2 * j + 1]) +
                           w1 * bf2f((unsigned short)p1[2 * j + 1]);
                r.u[j] = cvt2bf(lo, hi);
            }
            int off = (row * 128 + st_q * 16) ^ ((row & 7) << 4);
            *(short8*)((char*)As + off) = r.s;
            int br = n0 + row;
            *(short8*)((char*)Bs + off) =
                load8f(wout, (size_t)br * 512 + k0 + st_q * 8);
        }
        __syncthreads();

        const int rowa0 = wm * 64 + l31, rowa1 = wm * 64 + 32 + l31;
        const int rowb0 = wn * 64 + l31, rowb1 = wn * 64 + 32 + l31;
#pragma unroll
        for (int ks = 0; ks < 4; ++ks) {
            short8 a0 = *(const short8*)((char*)As +
                ((rowa0 * 128 + ks * 32 + h * 16) ^ ((rowa0 & 7) << 4)));
            short8 a1 = *(const short8*)((char*)As +
                ((rowa1 * 128 + ks * 32 + h * 16) ^ ((rowa1 & 7) << 4)));
            short8 b0 = *(const short8*)((char*)Bs +
                ((rowb0 * 128 + ks * 32 + h * 16) ^ ((rowb0 & 7) << 4)));
            short8 b1 = *(const short8*)((char*)Bs +
                ((rowb1 * 128 + ks * 32 + h * 16) ^ ((rowb1 & 7) << 4)));
            acc[0][0] = mfma_bf(a0, b0, acc[0][0]);
            acc[0][1] = mfma_bf(a0, b1, acc[0][1]);
            acc[1][0] = mfma_bf(a1, b0, acc[1][0]);
            acc[1][1] = mfma_bf(a1, b1, acc[1][1]);
        }
    }

#pragma unroll
    for (int mt = 0; mt < 2; ++mt)
#pragma unroll
        for (int nt = 0; nt < 2; ++nt) {
            int Ncol = n0 + wn * 64 + nt * 32 + l31;
#pragma unroll
            for (int r = 0; r < 16; ++r) {
                int Mrow = m0 + wm * 64 + mt * 32 + (r & 3) + ((r >> 2) << 3) + h * 4;
                o_f[(size_t)Mrow * 512 + Ncol] = acc[mt][nt][r];
            }
        }
}

// ---------------------------------------------------------------- host
extern "C" void kernel_launch(void* const* d_in, const int* in_sizes, int n_in,
                              void* d_out, int out_size, void* d_ws, size_t ws_size,
                              hipStream_t stream) {
    const float* x    = (const float*)d_in[0];
    const float* pe   = (const float*)d_in[1];
    const unsigned char* mask = (const unsigned char*)d_in[2];
    const float* wqkv = (const float*)d_in[3];
    const float* wpos = (const float*)d_in[4];
    const float* wout = (const float*)d_in[5];
    const float* bu   = (const float*)d_in[6];
    const float* bv   = (const float*)d_in[7];
    float* out = (float*)d_out;

    char* ws = (char*)d_ws;
    unsigned short* qu    = (unsigned short*)(ws + 0);
    unsigned short* qv    = (unsigned short*)(ws + 4194304);
    unsigned short* kb    = (unsigned short*)(ws + 8388608);
    unsigned short* vt    = (unsigned short*)(ws + 12582912);
    unsigned short* posb  = (unsigned short*)(ws + 16777216);   // 4,193,280 B
    unsigned long long* maskw = (unsigned long long*)(ws + 20971520); // 1 MB
    unsigned short* opart = (unsigned short*)(ws + 22020096);   // 8,388,608 B
    float* mstat          = (float*)(ws + 30408704);            // 262,144 B
    float* lstat          = (float*)(ws + 30670848);            // 262,144 B
    // total ws use ~31 MB, no overlaps

    front_kernel<<<640, 256, 0, stream>>>(
        x, wqkv, pe, wpos, qu, qv, kb, vt, posb, bu, bv, mask, maskw);
    attn_kernel<<<1024, 128, 0, stream>>>(
        qu, qv, kb, vt, posb, maskw, opart, mstat, lstat);
    back_kernel<<<128, 256, 0, stream>>>(
        opart, wout, mstat, lstat, out);
}